// Round 9
// baseline (470.980 us; speedup 1.0000x reference)
//
#include <hip/hip_runtime.h>
#include <cmath>

typedef _Float16 f16x8 __attribute__((ext_vector_type(8)));
typedef _Float16 f16x4 __attribute__((ext_vector_type(4)));
typedef float    f32x4 __attribute__((ext_vector_type(4)));

#define LOG2E 1.4426950408889634f

// async global->LDS, 16B per lane. LDS dest is wave-uniform base + lane*16.
// Global src is per-lane (we pre-swizzle it so LDS stays linear).
__device__ __forceinline__ void load_lds16(const void* g, void* l) {
  __builtin_amdgcn_global_load_lds(
      (const __attribute__((address_space(1))) unsigned int*)g,
      (__attribute__((address_space(3))) unsigned int*)l, 16, 0, 0);
}

// ---------------- fp32 -> fp16 convert ----------------
__global__ __launch_bounds__(256) void cvt_f32_f16(const float* __restrict__ in,
                                                   _Float16* __restrict__ out,
                                                   int n4) {
  int i = blockIdx.x * blockDim.x + threadIdx.x;
  int stride = gridDim.x * blockDim.x;
  for (; i < n4; i += stride) {
    float4 v = ((const float4*)in)[i];
    f16x4 h = { (_Float16)v.x, (_Float16)v.y, (_Float16)v.z, (_Float16)v.w };
    ((f16x4*)out)[i] = h;
  }
}

__global__ __launch_bounds__(256) void cvt_w4(const float* __restrict__ w0,
                                              const float* __restrict__ w1,
                                              const float* __restrict__ w2,
                                              const float* __restrict__ w3,
                                              _Float16* __restrict__ o0,
                                              _Float16* __restrict__ o1,
                                              _Float16* __restrict__ o2,
                                              _Float16* __restrict__ o3,
                                              int n4) {
  const float* in = (blockIdx.y == 0) ? w0 : (blockIdx.y == 1) ? w1
                  : (blockIdx.y == 2) ? w2 : w3;
  _Float16* out = (blockIdx.y == 0) ? o0 : (blockIdx.y == 1) ? o1
                : (blockIdx.y == 2) ? o2 : o3;
  int i = blockIdx.x * blockDim.x + threadIdx.x;
  int stride = gridDim.x * blockDim.x;
  for (; i < n4; i += stride) {
    float4 v = ((const float4*)in)[i];
    f16x4 h = { (_Float16)v.x, (_Float16)v.y, (_Float16)v.z, (_Float16)v.w };
    ((f16x4*)out)[i] = h;
  }
}

// =========== 8-phase 256x256 GEMM (QKV projections, fused via blockIdx.z) ===========
// 512 thr / 8 waves (wm 0..1 x wn 0..3); wave tile 128x64; acc[8][4] f32x4.
// BK=64 split in 2 k-halves; LDS [2 buf][2 kh][256 row][32 f16] (A and B, 128 KB):
// each k-half is a CONTIGUOUS 16 KB stage unit (global_load_lds needs linear dest).
// Swizzle within k-half: 16B slot ^= (row>>2)&3, applied on the pre-swizzled
// global source AND the ds_read address (same involution) -> bank-minimal b128.
// Schedule per K-tile t (buf = t&1):
//   kh=0: vmcnt(4)+bar  (certifies A/B(t,kh0), staged 1 tile ago; leaves 4 newest
//         loads in flight -> never drain to 0)
//         phase og0: read B(kh0),A rows 0-63 | stage A(t+1,kh0) | 16 MFMA | bar
//         phase og1: read A rows 64-127      | stage B(t+1,kh0) | 16 MFMA
//   kh=1: vmcnt(4)+bar; phases og0/og1 staging A/B(t+1,kh1).
// WAR safe: stage t+1 -> buf^1, last read by tile t-1 before this tile's barrier.
__global__ __launch_bounds__(512, 2) void gemm_qkv_8p(
    const _Float16* __restrict__ Xh,
    const _Float16* __restrict__ Wq, const _Float16* __restrict__ Wk,
    const _Float16* __restrict__ Wv,
    _Float16* __restrict__ Qb, _Float16* __restrict__ Kb,
    _Float16* __restrict__ Vt, float qscale) {
  __shared__ _Float16 Asm[2][2][256][32];  // 64 KB
  __shared__ _Float16 Bsm[2][2][256][32];  // 64 KB

  const int tid = threadIdx.x;
  const int wave = tid >> 6, lane = tid & 63;
  const int g = lane >> 4, l15 = lane & 15;
  const int wm = wave >> 2, wn = wave & 3;
  const int z = blockIdx.z;
  const _Float16* Bw = (z == 0) ? Wq : (z == 1) ? Wk : Wv;
  const _Float16* Ab = Xh + (size_t)(blockIdx.x * 256) * 2048;
  const _Float16* Bb = Bw + (size_t)(blockIdx.y * 256) * 2048;

  // stage source precompute (2 x 16B per thread per unit)
  const int r0 = tid >> 2, r1 = r0 + 128;
  const int g0 = (tid & 3) ^ ((r0 >> 2) & 3);
  const int g1 = (tid & 3) ^ ((r1 >> 2) & 3);
  const size_t o0 = (size_t)r0 * 2048 + g0 * 8;
  const size_t o1 = (size_t)r1 * 2048 + g1 * 8;

  auto stageA = [&](int buf, int kh, int k0) {
    char* d = (char*)Asm + (size_t)(buf * 2 + kh) * 16384 + wave * 1024;
    load_lds16(Ab + o0 + k0 + kh * 32, d);
    load_lds16(Ab + o1 + k0 + kh * 32, d + 8192);
  };
  auto stageB = [&](int buf, int kh, int k0) {
    char* d = (char*)Bsm + (size_t)(buf * 2 + kh) * 16384 + wave * 1024;
    load_lds16(Bb + o0 + k0 + kh * 32, d);
    load_lds16(Bb + o1 + k0 + kh * 32, d + 8192);
  };

  f32x4 acc[8][4] = {};

  // prologue: tile 0 fully staged into buf 0 (8 loads/thread)
  stageA(0, 0, 0); stageB(0, 0, 0);
  stageA(0, 1, 0); stageB(0, 1, 0);

  const int NT = 32;  // K=2048 / BK=64
#pragma unroll 2
  for (int t = 0; t < NT; ++t) {
    const int buf = t & 1;
    const int k0n = (t + 1) * 64;
    const bool pf = (t + 1 < NT);
#pragma unroll
    for (int kh = 0; kh < 2; ++kh) {
      if (pf || kh == 0)
        asm volatile("s_waitcnt vmcnt(4)" ::: "memory");
      else
        asm volatile("s_waitcnt vmcnt(0)" ::: "memory");
      __builtin_amdgcn_s_barrier();
      asm volatile("" ::: "memory");

      const char* Al = (const char*)Asm + (size_t)(buf * 2 + kh) * 16384;
      const char* Bl = (const char*)Bsm + (size_t)(buf * 2 + kh) * 16384;

      f16x8 bfr[4];
#pragma unroll
      for (int cf = 0; cf < 4; ++cf) {
        int c = wn * 64 + cf * 16 + l15;
        bfr[cf] = *(const f16x8*)(Bl + c * 64 + ((g ^ ((c >> 2) & 3)) << 4));
      }
      // ---- phase og=0: rows 0-63 of wave tile ----
      {
        f16x8 af[4];
#pragma unroll
        for (int j = 0; j < 4; ++j) {
          int r = wm * 128 + j * 16 + l15;
          af[j] = *(const f16x8*)(Al + r * 64 + ((g ^ ((r >> 2) & 3)) << 4));
        }
        if (pf) stageA(buf ^ 1, kh, k0n);
        __builtin_amdgcn_s_setprio(1);
#pragma unroll
        for (int j = 0; j < 4; ++j)
#pragma unroll
          for (int cf = 0; cf < 4; ++cf)
            acc[j][cf] = __builtin_amdgcn_mfma_f32_16x16x32_f16(
                af[j], bfr[cf], acc[j][cf], 0, 0, 0);
        __builtin_amdgcn_s_setprio(0);
      }
      __builtin_amdgcn_s_barrier();
      asm volatile("" ::: "memory");
      // ---- phase og=1: rows 64-127 ----
      {
        f16x8 af[4];
#pragma unroll
        for (int j = 0; j < 4; ++j) {
          int r = wm * 128 + (4 + j) * 16 + l15;
          af[j] = *(const f16x8*)(Al + r * 64 + ((g ^ ((r >> 2) & 3)) << 4));
        }
        if (pf) stageB(buf ^ 1, kh, k0n);
        __builtin_amdgcn_s_setprio(1);
#pragma unroll
        for (int j = 0; j < 4; ++j)
#pragma unroll
          for (int cf = 0; cf < 4; ++cf)
            acc[4 + j][cf] = __builtin_amdgcn_mfma_f32_16x16x32_f16(
                af[j], bfr[cf], acc[4 + j][cf], 0, 0, 0);
        __builtin_amdgcn_s_setprio(0);
      }
    }
  }

  // ---- epilogue: scatter Q/K/V ----
  const float scale = (z == 0) ? qscale : 1.0f;
#pragma unroll
  for (int rf = 0; rf < 8; ++rf)
#pragma unroll
    for (int cf = 0; cf < 4; ++cf)
#pragma unroll
      for (int rr = 0; rr < 4; ++rr) {
        int row = blockIdx.x * 256 + wm * 128 + rf * 16 + g * 4 + rr;  // token
        int col = blockIdx.y * 256 + wn * 64 + cf * 16 + l15;          // feature
        float v = acc[rf][cf][rr] * scale;
        int b = row >> 11, sq = row & 2047, h = col >> 7, d = col & 127;
        if (z < 2) {
          _Float16* dst = (z == 0) ? Qb : Kb;
          dst[(((size_t)b * 16 + h) * 2048 + sq) * 128 + d] = (_Float16)v;
        } else {
          Vt[(((size_t)b * 16 + h) * 128 + d) * 2048 + sq] = (_Float16)v;
        }
      }
}

// ---------------- GEMM core (round-5 best: single-buffer 128^2) for gemm_out ----------------
__device__ __forceinline__ void gemm_core(const _Float16* __restrict__ A,
                                          const _Float16* __restrict__ B,
                                          _Float16* Asm, _Float16* Bsm,
                                          f32x4 acc[4][4]) {
  const int tid  = threadIdx.x;
  const int wave = tid >> 6, lane = tid & 63;
  const int g = lane >> 4, l15 = lane & 15;
  const int wm = wave >> 1, wn = wave & 1;
  const int srow = tid >> 2, sslot = tid & 3;

  const _Float16* Abase = A + (size_t)(blockIdx.x * 128) * 2048;
  const _Float16* Bbase = B + (size_t)(blockIdx.y * 128) * 2048;

  for (int k0 = 0; k0 < 2048; k0 += 32) {
#pragma unroll
    for (int i = 0; i < 2; ++i) {
      int row = i * 64 + srow;
      int sp  = sslot ^ ((row >> 1) & 3);
      load_lds16(Abase + (size_t)row * 2048 + k0 + sp * 8,
                 (char*)Asm + i * 4096 + wave * 1024);
      load_lds16(Bbase + (size_t)row * 2048 + k0 + sp * 8,
                 (char*)Bsm + i * 4096 + wave * 1024);
    }
    __syncthreads();

    f16x8 af[4], bf[4];
#pragma unroll
    for (int mi = 0; mi < 4; ++mi) {
      int row = wm * 64 + mi * 16 + l15;
      af[mi] = *(const f16x8*)((const char*)Asm + row * 64 +
                               ((g ^ ((row >> 1) & 3)) << 4));
    }
#pragma unroll
    for (int ni = 0; ni < 4; ++ni) {
      int row = wn * 64 + ni * 16 + l15;
      bf[ni] = *(const f16x8*)((const char*)Bsm + row * 64 +
                               ((g ^ ((row >> 1) & 3)) << 4));
    }
#pragma unroll
    for (int mi = 0; mi < 4; ++mi)
#pragma unroll
      for (int ni = 0; ni < 4; ++ni)
        acc[mi][ni] = __builtin_amdgcn_mfma_f32_16x16x32_f16(af[mi], bf[ni],
                                                             acc[mi][ni], 0, 0, 0);
    __syncthreads();
  }
}

// Final projection: AO[4096x2048] fp16 @ Wo^T -> fp32 out.
__global__ __launch_bounds__(256) void gemm_out(
    const _Float16* __restrict__ AO, const _Float16* __restrict__ Wo,
    float* __restrict__ C) {
  __shared__ _Float16 Asm[128 * 32], Bsm[128 * 32];
  f32x4 acc[4][4] = {};
  gemm_core(AO, Wo, Asm, Bsm, acc);

  const int tid = threadIdx.x;
  const int wave = tid >> 6, lane = tid & 63;
  const int g = lane >> 4, l15 = lane & 15;
  const int wm = wave >> 1, wn = wave & 1;
#pragma unroll
  for (int mi = 0; mi < 4; ++mi)
#pragma unroll
    for (int ni = 0; ni < 4; ++ni)
#pragma unroll
      for (int r = 0; r < 4; ++r) {
        int row = blockIdx.x * 128 + wm * 64 + mi * 16 + g * 4 + r;
        int col = blockIdx.y * 128 + wn * 64 + ni * 16 + l15;
        C[(size_t)row * 2048 + col] = acc[mi][ni][r];
      }
}

// ---------------- causal flash attention (unchanged, verified) ----------------
__global__ __launch_bounds__(256, 2) void attn_fwd(
    const _Float16* __restrict__ Qb, const _Float16* __restrict__ Kb,
    const _Float16* __restrict__ Vt, _Float16* __restrict__ AO) {
  const int id  = blockIdx.x;
  const int xcd = id & 7, j = id >> 3;
  const int bh  = xcd * 4 + (j & 3);
  const int qb  = 15 - (j >> 2);

  const int tid = threadIdx.x;
  const int wave = tid >> 6, lane = tid & 63;
  const int g = lane >> 4, l15 = lane & 15;

  __shared__ _Float16 Ksm[2][64 * 128];
  __shared__ _Float16 Vsm[2][64 * 128];
  __shared__ _Float16 Psm[4][32 * 64];

  const _Float16* qp =
      Qb + ((size_t)bh * 2048 + qb * 128 + wave * 32 + l15) * 128;
  f16x8 qf[2][4];
#pragma unroll
  for (int mi = 0; mi < 2; ++mi)
#pragma unroll
    for (int c = 0; c < 4; ++c)
      qf[mi][c] = *(const f16x8*)(qp + mi * 16 * 128 + c * 32 + g * 8);

  f32x4 po[2][8] = {};
  float m[2][4], lsum[2][4];
#pragma unroll
  for (int mi = 0; mi < 2; ++mi)
#pragma unroll
    for (int r = 0; r < 4; ++r) { m[mi][r] = -1e30f; lsum[mi][r] = 0.f; }

  char* Pb = (char*)&Psm[wave][0];
  const int NT  = 2 * qb + 2;
  const int NTw = 2 * qb + 1 + (wave >> 1);
  const int dt  = 2 * qb + (wave >> 1);

  const int k_i  = tid >> 4, k_sp = (tid & 15) ^ (tid >> 4);
  const int v_i  = tid >> 3, v_sp = (tid & 7) ^ ((tid >> 3) & 7);
  const _Float16* kbase = Kb + (size_t)bh * 2048 * 128;
  const _Float16* vbase = Vt + (size_t)bh * 128 * 2048;

  auto stage = [&](int buf, int t) {
    char* kdst = (char*)&Ksm[buf][0] + wave * 1024;
    char* vdst = (char*)&Vsm[buf][0] + wave * 1024;
    const _Float16* kb = kbase + (size_t)t * 64 * 128;
    const _Float16* vb = vbase + t * 64;
#pragma unroll
    for (int i = 0; i < 4; ++i) {
      load_lds16(kb + (size_t)(i * 16 + k_i) * 128 + k_sp * 8, kdst + i * 4096);
      load_lds16(vb + (size_t)(i * 32 + v_i) * 2048 + v_sp * 8, vdst + i * 4096);
    }
  };

  stage(0, 0);
  __syncthreads();

  int buf = 0;
  for (int t = 0; t < NT; ++t) {
    if (t + 1 < NT) stage(buf ^ 1, t + 1);

    if (t < NTw) {
      const char* Kl = (const char*)&Ksm[buf][0];
      const char* Vl = (const char*)&Vsm[buf][0];

      f32x4 s[2][4];
      __builtin_amdgcn_s_setprio(1);
#pragma unroll
      for (int n = 0; n < 4; ++n) {
        f32x4 a0 = {0.f, 0.f, 0.f, 0.f}, a1 = {0.f, 0.f, 0.f, 0.f};
#pragma unroll
        for (int c = 0; c < 4; ++c) {
          int slot = (c * 4 + g) ^ l15;
          f16x8 kf = *(const f16x8*)(Kl + (n * 16 + l15) * 256 + (slot << 4));
          a0 = __builtin_amdgcn_mfma_f32_16x16x32_f16(qf[0][c], kf, a0, 0, 0, 0);
          a1 = __builtin_amdgcn_mfma_f32_16x16x32_f16(qf[1][c], kf, a1, 0, 0, 0);
        }
        s[0][n] = a0; s[1][n] = a1;
      }
      __builtin_amdgcn_s_setprio(0);

      if (t == dt) {
#pragma unroll
        for (int mi = 0; mi < 2; ++mi)
#pragma unroll
          for (int n = 0; n < 4; ++n)
#pragma unroll
            for (int r = 0; r < 4; ++r) {
              int key = t * 64 + n * 16 + l15;
              int qr  = qb * 128 + wave * 32 + mi * 16 + g * 4 + r;
              if (key > qr) s[mi][n][r] = -1e30f;
            }
      }

#pragma unroll
      for (int mi = 0; mi < 2; ++mi)
#pragma unroll
        for (int r = 0; r < 4; ++r) {
          float mx = fmaxf(fmaxf(s[mi][0][r], s[mi][1][r]),
                           fmaxf(s[mi][2][r], s[mi][3][r]));
#pragma unroll
          for (int off = 1; off < 16; off <<= 1) mx = fmaxf(mx, __shfl_xor(mx, off));
          float mn = fmaxf(m[mi][r], mx);
          float sc = exp2f(m[mi][r] - mn);
          m[mi][r] = mn;
          float rs = 0.f;
#pragma unroll
          for (int n = 0; n < 4; ++n) {
            float p = exp2f(s[mi][n][r] - mn);
            s[mi][n][r] = p;
            rs += p;
          }
#pragma unroll
          for (int off = 1; off < 16; off <<= 1) rs += __shfl_xor(rs, off);
          lsum[mi][r] = lsum[mi][r] * sc + rs;
#pragma unroll
          for (int no = 0; no < 8; ++no) po[mi][no][r] *= sc;
        }

#pragma unroll
      for (int mi = 0; mi < 2; ++mi)
#pragma unroll
        for (int n = 0; n < 4; ++n)
#pragma unroll
          for (int r = 0; r < 4; ++r) {
            int row = mi * 16 + g * 4 + r, key = n * 16 + l15;
            *(_Float16*)(Pb + row * 128 + (((key >> 3) ^ (row & 7)) << 4) +
                         (key & 7) * 2) = (_Float16)s[mi][n][r];
          }

      f16x8 pf[2][2];
#pragma unroll
      for (int mi = 0; mi < 2; ++mi)
#pragma unroll
        for (int kc = 0; kc < 2; ++kc) {
          int slot = (kc * 4 + g) ^ (l15 & 7);
          pf[mi][kc] = *(const f16x8*)(Pb + (mi * 16 + l15) * 128 + (slot << 4));
        }
      __builtin_amdgcn_s_setprio(1);
#pragma unroll
      for (int no = 0; no < 8; ++no)
#pragma unroll
        for (int kc = 0; kc < 2; ++kc) {
          int vrow = no * 16 + l15;
          int slot = (kc * 4 + g) ^ (l15 & 7);
          f16x8 vf = *(const f16x8*)(Vl + vrow * 128 + (slot << 4));
          po[0][no] = __builtin_amdgcn_mfma_f32_16x16x32_f16(pf[0][kc], vf,
                                                             po[0][no], 0, 0, 0);
          po[1][no] = __builtin_amdgcn_mfma_f32_16x16x32_f16(pf[1][kc], vf,
                                                             po[1][no], 0, 0, 0);
        }
      __builtin_amdgcn_s_setprio(0);
    }

    __syncthreads();
    buf ^= 1;
  }

  const int b = bh >> 4, h = bh & 15;
#pragma unroll
  for (int mi = 0; mi < 2; ++mi)
#pragma unroll
    for (int r = 0; r < 4; ++r) {
      float inv = 1.0f / lsum[mi][r];
      size_t row = (size_t)b * 2048 + qb * 128 + wave * 32 + mi * 16 + g * 4 + r;
#pragma unroll
      for (int no = 0; no < 8; ++no) {
        int col = h * 128 + no * 16 + l15;
        AO[row * 2048 + col] = (_Float16)(po[mi][no][r] * inv);
      }
    }
}

extern "C" void kernel_launch(void* const* d_in, const int* in_sizes, int n_in,
                              void* d_out, int out_size, void* d_ws, size_t ws_size,
                              hipStream_t stream) {
  const float* X  = (const float*)d_in[0];
  const float* Wq = (const float*)d_in[1];
  const float* Wk = (const float*)d_in[2];
  const float* Wv = (const float*)d_in[3];
  const float* Wo = (const float*)d_in[4];
  float* out = (float*)d_out;

  char* ws = (char*)d_ws;
  _Float16* Xh  = (_Float16*)(ws);                    // 16 MB
  _Float16* Wqh = (_Float16*)(ws + (16u << 20));      //  8 MB
  _Float16* Wkh = (_Float16*)(ws + (24u << 20));      //  8 MB
  _Float16* Wvh = (_Float16*)(ws + (32u << 20));      //  8 MB
  _Float16* Woh = (_Float16*)(ws + (40u << 20));      //  8 MB
  _Float16* Qb  = (_Float16*)(ws + (48u << 20));      // 16 MB [B,H,S,D]
  _Float16* Kb  = (_Float16*)(ws + (64u << 20));      // 16 MB [B,H,S,D]
  _Float16* Vt  = (_Float16*)(ws + (80u << 20));      // 16 MB [B,H,D,S]
  _Float16* AO  = (_Float16*)(ws + (96u << 20));      // 16 MB -> 112 MB total

  cvt_f32_f16<<<2048, 256, 0, stream>>>(X, Xh, 8388608 / 4);
  cvt_w4<<<dim3(512, 4), 256, 0, stream>>>(Wq, Wk, Wv, Wo, Wqh, Wkh, Wvh, Woh,
                                           4194304 / 4);

  const float qscale = LOG2E / sqrtf(128.0f);
  gemm_qkv_8p<<<dim3(16, 8, 3), 512, 0, stream>>>(Xh, Wqh, Wkh, Wvh, Qb, Kb, Vt,
                                                  qscale);
  attn_fwd<<<512, 256, 0, stream>>>(Qb, Kb, Vt, AO);
  gemm_out<<<dim3(32, 16), 256, 0, stream>>>(AO, Woh, out);
}

// Round 10
// 454.119 us; speedup vs baseline: 1.0371x; 1.0371x over previous
//
#include <hip/hip_runtime.h>
#include <cmath>

typedef _Float16 f16x8 __attribute__((ext_vector_type(8)));
typedef _Float16 f16x4 __attribute__((ext_vector_type(4)));
typedef float    f32x4 __attribute__((ext_vector_type(4)));

#define LOG2E 1.4426950408889634f

// async global->LDS, 16B per lane. LDS dest is wave-uniform base + lane*16.
// Global src is per-lane (we pre-swizzle it so LDS stays linear).
__device__ __forceinline__ void load_lds16(const void* g, void* l) {
  __builtin_amdgcn_global_load_lds(
      (const __attribute__((address_space(1))) unsigned int*)g,
      (__attribute__((address_space(3))) unsigned int*)l, 16, 0, 0);
}

// ---------------- fp32 -> fp16 convert (X + 4 weights in 2 launches) ----------------
__global__ __launch_bounds__(256) void cvt_f32_f16(const float* __restrict__ in,
                                                   _Float16* __restrict__ out,
                                                   int n4) {
  int i = blockIdx.x * blockDim.x + threadIdx.x;
  int stride = gridDim.x * blockDim.x;
  for (; i < n4; i += stride) {
    float4 v = ((const float4*)in)[i];
    f16x4 h = { (_Float16)v.x, (_Float16)v.y, (_Float16)v.z, (_Float16)v.w };
    ((f16x4*)out)[i] = h;
  }
}

__global__ __launch_bounds__(256) void cvt_w4(const float* __restrict__ w0,
                                              const float* __restrict__ w1,
                                              const float* __restrict__ w2,
                                              const float* __restrict__ w3,
                                              _Float16* __restrict__ o0,
                                              _Float16* __restrict__ o1,
                                              _Float16* __restrict__ o2,
                                              _Float16* __restrict__ o3,
                                              int n4) {
  const float* in = (blockIdx.y == 0) ? w0 : (blockIdx.y == 1) ? w1
                  : (blockIdx.y == 2) ? w2 : w3;
  _Float16* out = (blockIdx.y == 0) ? o0 : (blockIdx.y == 1) ? o1
                : (blockIdx.y == 2) ? o2 : o3;
  int i = blockIdx.x * blockDim.x + threadIdx.x;
  int stride = gridDim.x * blockDim.x;
  for (; i < n4; i += stride) {
    float4 v = ((const float4*)in)[i];
    f16x4 h = { (_Float16)v.x, (_Float16)v.y, (_Float16)v.z, (_Float16)v.w };
    ((f16x4*)out)[i] = h;
  }
}

// ---------------- GEMM core (verified best: single-buffer 128^2, 0 conflicts) ----------------
// 2-barrier loop; 3 blocks/CU of TLP hides staging latency implicitly (m114).
// Swizzle slot ^= ((row>>1)&3) on pre-swizzled global source + ds_read addr.
__device__ __forceinline__ void gemm_core(const _Float16* __restrict__ A,
                                          const _Float16* __restrict__ B,
                                          _Float16* Asm, _Float16* Bsm,
                                          f32x4 acc[4][4]) {
  const int tid  = threadIdx.x;
  const int wave = tid >> 6, lane = tid & 63;
  const int g = lane >> 4, l15 = lane & 15;
  const int wm = wave >> 1, wn = wave & 1;
  const int srow = tid >> 2, sslot = tid & 3;

  const _Float16* Abase = A + (size_t)(blockIdx.x * 128) * 2048;
  const _Float16* Bbase = B + (size_t)(blockIdx.y * 128) * 2048;

  for (int k0 = 0; k0 < 2048; k0 += 32) {
#pragma unroll
    for (int i = 0; i < 2; ++i) {
      int row = i * 64 + srow;
      int sp  = sslot ^ ((row >> 1) & 3);
      load_lds16(Abase + (size_t)row * 2048 + k0 + sp * 8,
                 (char*)Asm + i * 4096 + wave * 1024);
      load_lds16(Bbase + (size_t)row * 2048 + k0 + sp * 8,
                 (char*)Bsm + i * 4096 + wave * 1024);
    }
    __syncthreads();

    f16x8 af[4], bf[4];
#pragma unroll
    for (int mi = 0; mi < 4; ++mi) {
      int row = wm * 64 + mi * 16 + l15;
      af[mi] = *(const f16x8*)((const char*)Asm + row * 64 +
                               ((g ^ ((row >> 1) & 3)) << 4));
    }
#pragma unroll
    for (int ni = 0; ni < 4; ++ni) {
      int row = wn * 64 + ni * 16 + l15;
      bf[ni] = *(const f16x8*)((const char*)Bsm + row * 64 +
                               ((g ^ ((row >> 1) & 3)) << 4));
    }
#pragma unroll
    for (int mi = 0; mi < 4; ++mi)
#pragma unroll
      for (int ni = 0; ni < 4; ++ni)
        acc[mi][ni] = __builtin_amdgcn_mfma_f32_16x16x32_f16(af[mi], bf[ni],
                                                             acc[mi][ni], 0, 0, 0);
    __syncthreads();
  }
}

// One projection per launch (z passed as arg) so per-kernel timings are
// visible in the profile (attribution round).
__global__ __launch_bounds__(256) void gemm_qkv(
    const _Float16* __restrict__ Xh, const _Float16* __restrict__ W,
    _Float16* __restrict__ Qb, _Float16* __restrict__ Kb,
    _Float16* __restrict__ Vt, float qscale, int z) {
  __shared__ _Float16 Asm[128 * 32], Bsm[128 * 32];
  f32x4 acc[4][4] = {};
  gemm_core(Xh, W, Asm, Bsm, acc);

  const int tid = threadIdx.x;
  const int wave = tid >> 6, lane = tid & 63;
  const int g = lane >> 4, l15 = lane & 15;
  const int wm = wave >> 1, wn = wave & 1;
  const float scale = (z == 0) ? qscale : 1.0f;
#pragma unroll
  for (int mi = 0; mi < 4; ++mi)
#pragma unroll
    for (int ni = 0; ni < 4; ++ni)
#pragma unroll
      for (int r = 0; r < 4; ++r) {
        int row = blockIdx.x * 128 + wm * 64 + mi * 16 + g * 4 + r;  // token
        int col = blockIdx.y * 128 + wn * 64 + ni * 16 + l15;        // feature
        float v = acc[mi][ni][r] * scale;
        int b = row >> 11, sq = row & 2047, h = col >> 7, d = col & 127;
        if (z < 2) {
          _Float16* dst = (z == 0) ? Qb : Kb;
          dst[(((size_t)b * 16 + h) * 2048 + sq) * 128 + d] = (_Float16)v;
        } else {
          Vt[(((size_t)b * 16 + h) * 128 + d) * 2048 + sq] = (_Float16)v;
        }
      }
}

// Final projection: AO[4096x2048] fp16 @ Wo^T -> fp32 out.
__global__ __launch_bounds__(256) void gemm_out(
    const _Float16* __restrict__ AO, const _Float16* __restrict__ Wo,
    float* __restrict__ C) {
  __shared__ _Float16 Asm[128 * 32], Bsm[128 * 32];
  f32x4 acc[4][4] = {};
  gemm_core(AO, Wo, Asm, Bsm, acc);

  const int tid = threadIdx.x;
  const int wave = tid >> 6, lane = tid & 63;
  const int g = lane >> 4, l15 = lane & 15;
  const int wm = wave >> 1, wn = wave & 1;
#pragma unroll
  for (int mi = 0; mi < 4; ++mi)
#pragma unroll
    for (int ni = 0; ni < 4; ++ni)
#pragma unroll
      for (int r = 0; r < 4; ++r) {
        int row = blockIdx.x * 128 + wm * 64 + mi * 16 + g * 4 + r;
        int col = blockIdx.y * 128 + wn * 64 + ni * 16 + l15;
        C[(size_t)row * 2048 + col] = acc[mi][ni][r];
      }
}

// ---------------- causal flash attention (round-5 verified) ----------------
__global__ __launch_bounds__(256, 2) void attn_fwd(
    const _Float16* __restrict__ Qb, const _Float16* __restrict__ Kb,
    const _Float16* __restrict__ Vt, _Float16* __restrict__ AO) {
  const int id  = blockIdx.x;
  const int xcd = id & 7, j = id >> 3;
  const int bh  = xcd * 4 + (j & 3);
  const int qb  = 15 - (j >> 2);

  const int tid = threadIdx.x;
  const int wave = tid >> 6, lane = tid & 63;
  const int g = lane >> 4, l15 = lane & 15;

  __shared__ _Float16 Ksm[2][64 * 128];
  __shared__ _Float16 Vsm[2][64 * 128];
  __shared__ _Float16 Psm[4][32 * 64];

  const _Float16* qp =
      Qb + ((size_t)bh * 2048 + qb * 128 + wave * 32 + l15) * 128;
  f16x8 qf[2][4];
#pragma unroll
  for (int mi = 0; mi < 2; ++mi)
#pragma unroll
    for (int c = 0; c < 4; ++c)
      qf[mi][c] = *(const f16x8*)(qp + mi * 16 * 128 + c * 32 + g * 8);

  f32x4 po[2][8] = {};
  float m[2][4], lsum[2][4];
#pragma unroll
  for (int mi = 0; mi < 2; ++mi)
#pragma unroll
    for (int r = 0; r < 4; ++r) { m[mi][r] = -1e30f; lsum[mi][r] = 0.f; }

  char* Pb = (char*)&Psm[wave][0];
  const int NT  = 2 * qb + 2;
  const int NTw = 2 * qb + 1 + (wave >> 1);
  const int dt  = 2 * qb + (wave >> 1);

  const int k_i  = tid >> 4, k_sp = (tid & 15) ^ (tid >> 4);
  const int v_i  = tid >> 3, v_sp = (tid & 7) ^ ((tid >> 3) & 7);
  const _Float16* kbase = Kb + (size_t)bh * 2048 * 128;
  const _Float16* vbase = Vt + (size_t)bh * 128 * 2048;

  auto stage = [&](int buf, int t) {
    char* kdst = (char*)&Ksm[buf][0] + wave * 1024;
    char* vdst = (char*)&Vsm[buf][0] + wave * 1024;
    const _Float16* kb = kbase + (size_t)t * 64 * 128;
    const _Float16* vb = vbase + t * 64;
#pragma unroll
    for (int i = 0; i < 4; ++i) {
      load_lds16(kb + (size_t)(i * 16 + k_i) * 128 + k_sp * 8, kdst + i * 4096);
      load_lds16(vb + (size_t)(i * 32 + v_i) * 2048 + v_sp * 8, vdst + i * 4096);
    }
  };

  stage(0, 0);
  __syncthreads();

  int buf = 0;
  for (int t = 0; t < NT; ++t) {
    if (t + 1 < NT) stage(buf ^ 1, t + 1);

    if (t < NTw) {
      const char* Kl = (const char*)&Ksm[buf][0];
      const char* Vl = (const char*)&Vsm[buf][0];

      f32x4 s[2][4];
      __builtin_amdgcn_s_setprio(1);
#pragma unroll
      for (int n = 0; n < 4; ++n) {
        f32x4 a0 = {0.f, 0.f, 0.f, 0.f}, a1 = {0.f, 0.f, 0.f, 0.f};
#pragma unroll
        for (int c = 0; c < 4; ++c) {
          int slot = (c * 4 + g) ^ l15;
          f16x8 kf = *(const f16x8*)(Kl + (n * 16 + l15) * 256 + (slot << 4));
          a0 = __builtin_amdgcn_mfma_f32_16x16x32_f16(qf[0][c], kf, a0, 0, 0, 0);
          a1 = __builtin_amdgcn_mfma_f32_16x16x32_f16(qf[1][c], kf, a1, 0, 0, 0);
        }
        s[0][n] = a0; s[1][n] = a1;
      }
      __builtin_amdgcn_s_setprio(0);

      if (t == dt) {
#pragma unroll
        for (int mi = 0; mi < 2; ++mi)
#pragma unroll
          for (int n = 0; n < 4; ++n)
#pragma unroll
            for (int r = 0; r < 4; ++r) {
              int key = t * 64 + n * 16 + l15;
              int qr  = qb * 128 + wave * 32 + mi * 16 + g * 4 + r;
              if (key > qr) s[mi][n][r] = -1e30f;
            }
      }

#pragma unroll
      for (int mi = 0; mi < 2; ++mi)
#pragma unroll
        for (int r = 0; r < 4; ++r) {
          float mx = fmaxf(fmaxf(s[mi][0][r], s[mi][1][r]),
                           fmaxf(s[mi][2][r], s[mi][3][r]));
#pragma unroll
          for (int off = 1; off < 16; off <<= 1) mx = fmaxf(mx, __shfl_xor(mx, off));
          float mn = fmaxf(m[mi][r], mx);
          float sc = exp2f(m[mi][r] - mn);
          m[mi][r] = mn;
          float rs = 0.f;
#pragma unroll
          for (int n = 0; n < 4; ++n) {
            float p = exp2f(s[mi][n][r] - mn);
            s[mi][n][r] = p;
            rs += p;
          }
#pragma unroll
          for (int off = 1; off < 16; off <<= 1) rs += __shfl_xor(rs, off);
          lsum[mi][r] = lsum[mi][r] * sc + rs;
#pragma unroll
          for (int no = 0; no < 8; ++no) po[mi][no][r] *= sc;
        }

#pragma unroll
      for (int mi = 0; mi < 2; ++mi)
#pragma unroll
        for (int n = 0; n < 4; ++n)
#pragma unroll
          for (int r = 0; r < 4; ++r) {
            int row = mi * 16 + g * 4 + r, key = n * 16 + l15;
            *(_Float16*)(Pb + row * 128 + (((key >> 3) ^ (row & 7)) << 4) +
                         (key & 7) * 2) = (_Float16)s[mi][n][r];
          }

      f16x8 pf[2][2];
#pragma unroll
      for (int mi = 0; mi < 2; ++mi)
#pragma unroll
        for (int kc = 0; kc < 2; ++kc) {
          int slot = (kc * 4 + g) ^ (l15 & 7);
          pf[mi][kc] = *(const f16x8*)(Pb + (mi * 16 + l15) * 128 + (slot << 4));
        }
      __builtin_amdgcn_s_setprio(1);
#pragma unroll
      for (int no = 0; no < 8; ++no)
#pragma unroll
        for (int kc = 0; kc < 2; ++kc) {
          int vrow = no * 16 + l15;
          int slot = (kc * 4 + g) ^ (l15 & 7);
          f16x8 vf = *(const f16x8*)(Vl + vrow * 128 + (slot << 4));
          po[0][no] = __builtin_amdgcn_mfma_f32_16x16x32_f16(pf[0][kc], vf,
                                                             po[0][no], 0, 0, 0);
          po[1][no] = __builtin_amdgcn_mfma_f32_16x16x32_f16(pf[1][kc], vf,
                                                             po[1][no], 0, 0, 0);
        }
      __builtin_amdgcn_s_setprio(0);
    }

    __syncthreads();
    buf ^= 1;
  }

  const int b = bh >> 4, h = bh & 15;
#pragma unroll
  for (int mi = 0; mi < 2; ++mi)
#pragma unroll
    for (int r = 0; r < 4; ++r) {
      float inv = 1.0f / lsum[mi][r];
      size_t row = (size_t)b * 2048 + qb * 128 + wave * 32 + mi * 16 + g * 4 + r;
#pragma unroll
      for (int no = 0; no < 8; ++no) {
        int col = h * 128 + no * 16 + l15;
        AO[row * 2048 + col] = (_Float16)(po[mi][no][r] * inv);
      }
    }
}

extern "C" void kernel_launch(void* const* d_in, const int* in_sizes, int n_in,
                              void* d_out, int out_size, void* d_ws, size_t ws_size,
                              hipStream_t stream) {
  const float* X  = (const float*)d_in[0];
  const float* Wq = (const float*)d_in[1];
  const float* Wk = (const float*)d_in[2];
  const float* Wv = (const float*)d_in[3];
  const float* Wo = (const float*)d_in[4];
  float* out = (float*)d_out;

  char* ws = (char*)d_ws;
  _Float16* Xh  = (_Float16*)(ws);                    // 16 MB
  _Float16* Wqh = (_Float16*)(ws + (16u << 20));      //  8 MB
  _Float16* Wkh = (_Float16*)(ws + (24u << 20));      //  8 MB
  _Float16* Wvh = (_Float16*)(ws + (32u << 20));      //  8 MB
  _Float16* Woh = (_Float16*)(ws + (40u << 20));      //  8 MB
  _Float16* Qb  = (_Float16*)(ws + (48u << 20));      // 16 MB [B,H,S,D]
  _Float16* Kb  = (_Float16*)(ws + (64u << 20));      // 16 MB [B,H,S,D]
  _Float16* Vt  = (_Float16*)(ws + (80u << 20));      // 16 MB [B,H,D,S]
  _Float16* AO  = (_Float16*)(ws + (96u << 20));      // 16 MB -> 112 MB total

  cvt_f32_f16<<<2048, 256, 0, stream>>>(X, Xh, 8388608 / 4);
  cvt_w4<<<dim3(512, 4), 256, 0, stream>>>(Wq, Wk, Wv, Wo, Wqh, Wkh, Wvh, Woh,
                                           4194304 / 4);

  const float qscale = LOG2E / sqrtf(128.0f);
  gemm_qkv<<<dim3(32, 16), 256, 0, stream>>>(Xh, Wqh, Qb, Kb, Vt, qscale, 0);
  gemm_qkv<<<dim3(32, 16), 256, 0, stream>>>(Xh, Wkh, Qb, Kb, Vt, qscale, 1);
  gemm_qkv<<<dim3(32, 16), 256, 0, stream>>>(Xh, Wvh, Qb, Kb, Vt, qscale, 2);
  attn_fwd<<<512, 256, 0, stream>>>(Qb, Kb, Vt, AO);
  gemm_out<<<dim3(32, 16), 256, 0, stream>>>(AO, Woh, out);
}